// Round 10
// baseline (386.470 us; speedup 1.0000x reference)
//
#include <hip/hip_runtime.h>
#include <cstdint>
#include <cstddef>

#define NFREQ 10
#define NN    65536
#define ENCD  42       // 2*(1+2*NFREQ)
#define K0    170      // ENCD + 128
#define S0    200      // h0 / W0t stride in fp16 elems (400B rows: 16B-aligned, 2-way banks)
#define S1    136      // hidden-layer stride (272B rows)
#define TM    128      // rows per block

typedef _Float16 f16;
typedef f16  f16x8 __attribute__((ext_vector_type(8)));
typedef float f32x4 __attribute__((ext_vector_type(4)));

// ---- workspace layout (bytes) ----
#define WS_ENC   0u          // uint32 [24][NN] : packed fp16 pairs of enc (cols 2d,2d+1), transposed
#define WS_BILIN 6291456u    // float4 [NN] : {fy, fx, asfloat(y0), asfloat(x0)}
#define WS_W0T   7340032u    // f16 [128][S0]  rows=out, cols=in; in>=170 zeroed
#define WS_W1T   7391232u    // f16 [128][S1]
#define WS_W2T   7426048u    // f16 [128][S1]
#define WS_WOUT  7460864u    // f32 [4][128]   rows=out-col (row 3 zero)

// Epilogue tanh: R1-verbatim (proven numerics; only 384 threads use it).
__device__ __forceinline__ float fast_tanh(float z) {
  z = fminf(fmaxf(z, -10.f), 10.f);           // avoid inf/inf
  float e = __expf(2.f * z);
  return (e - 1.f) * __builtin_amdgcn_rcpf(e + 1.f);
}
// gelu via sigmoid identity (R7-proven): ONE exp2 + ONE rcp, no NaN path.
__device__ __forceinline__ float gelu_fast(float x) {
  float z = 0.7978845608028654f * (x + 0.044715f * x * x * x);
  float e = __builtin_amdgcn_exp2f(-2.8853900817779268f * z);
  return x * __builtin_amdgcn_rcpf(1.f + e);
}

// ---------------- prep: posenc + bilinear params (R1-verbatim) ----------------
__global__ void prep_misc(const float* __restrict__ coords,
                          uint32_t* __restrict__ enc2, float4* __restrict__ bilin) {
  int n = blockIdx.x * blockDim.x + threadIdx.x;
  if (n >= NN) return;
  float cy = coords[2 * n + 0];
  float cx = coords[2 * n + 1];
  float e[48];
  e[0] = cy; e[1] = cx;
  float f = 3.14159265358979323846f;            // freqs[i] = 2^i * pi (exact doubling)
  #pragma unroll
  for (int i = 0; i < NFREQ; ++i) {
    float sy, cyv, sx, cxv;
    sincosf(cy * f, &sy, &cyv);
    sincosf(cx * f, &sx, &cxv);
    e[2 + 4 * i + 0] = sy;  e[2 + 4 * i + 1] = sx;
    e[2 + 4 * i + 2] = cyv; e[2 + 4 * i + 3] = cxv;
    f *= 2.0f;
  }
  #pragma unroll
  for (int k = ENCD; k < 48; ++k) e[k] = 0.f;
  #pragma unroll
  for (int d = 0; d < 24; ++d) {
    f16 lo = (f16)e[2 * d], hi = (f16)e[2 * d + 1];
    uint32_t u = (uint32_t)__builtin_bit_cast(uint16_t, lo) |
                 ((uint32_t)__builtin_bit_cast(uint16_t, hi) << 16);
    enc2[(size_t)d * NN + n] = u;
  }
  float ry = (cy + 1.f) * 0.5f * 63.f;
  float rx = (cx + 1.f) * 0.5f * 63.f;
  ry = fminf(fmaxf(ry, 0.f), 63.f);
  rx = fminf(fmaxf(rx, 0.f), 63.f);
  int y0 = min((int)ry, 62), x0 = min((int)rx, 62);
  bilin[n] = make_float4(ry - (float)y0, rx - (float)x0,
                         __int_as_float(y0), __int_as_float(x0));
}

// ---------------- prep: pack transposed fp16 weights (R1-verbatim) ----------------
__global__ void prep_w(const float* __restrict__ W0, const float* __restrict__ W1,
                       const float* __restrict__ W2, const float* __restrict__ Wo,
                       f16* __restrict__ w0t, f16* __restrict__ w1t,
                       f16* __restrict__ w2t, float* __restrict__ woutt) {
  int i = blockIdx.x * blockDim.x + threadIdx.x;
  const int n0 = 128 * S0, n1 = 128 * S1;
  if (i < n0) {
    int j = i / S0, k = i - j * S0;
    w0t[i] = (k < K0) ? (f16)W0[k * 128 + j] : (f16)0.f;
  } else if (i < n0 + n1) {
    int ii = i - n0; int j = ii / S1, k = ii - j * S1;
    w1t[ii] = (k < 128) ? (f16)W1[k * 128 + j] : (f16)0.f;
  } else if (i < n0 + 2 * n1) {
    int ii = i - n0 - n1; int j = ii / S1, k = ii - j * S1;
    w2t[ii] = (k < 128) ? (f16)W2[k * 128 + j] : (f16)0.f;
  } else if (i < n0 + 2 * n1 + 512) {
    int ii = i - n0 - 2 * n1; int oc = ii >> 7, k = ii & 127;
    woutt[ii] = (oc < 3) ? Wo[k * 3 + oc] : 0.f;
  }
}

// ---- K-chunk of 2 k-steps: batch 8 B-loads, PIN them live (rule #17), then MFMA ----
// The empty asm consumes each fragment, so the scheduler cannot sink the loads
// back into the MFMA loop (R7/R9 failure mode: VGPR stuck at 64, one vmcnt wait
// per kk). One latency exposure per chunk; 32 B-VGPRs pinned (keeps total <128).
template <int SW>
__device__ __forceinline__ void mlp_chunk2(const f16* a0p, const f16* a1p,
                                           const f16* wp, f32x4 (&acc)[2][4]) {
  f16x8 bf[2][4];
  #pragma unroll
  for (int kk = 0; kk < 2; ++kk)
    #pragma unroll
    for (int ns = 0; ns < 4; ++ns)
      bf[kk][ns] = *(const f16x8*)(wp + (16 * ns) * SW + kk * 32);
  #pragma unroll
  for (int kk = 0; kk < 2; ++kk)
    #pragma unroll
    for (int ns = 0; ns < 4; ++ns)
      asm volatile("" : "+v"(bf[kk][ns]));    // pin: all 8 loads complete HERE
  #pragma unroll
  for (int kk = 0; kk < 2; ++kk) {
    f16x8 a0 = *(const f16x8*)(a0p + kk * 32);
    f16x8 a1 = *(const f16x8*)(a1p + kk * 32);
    #pragma unroll
    for (int ns = 0; ns < 4; ++ns) {
      acc[0][ns] = __builtin_amdgcn_mfma_f32_16x16x32_f16(a0, bf[kk][ns], acc[0][ns], 0, 0, 0);
      acc[1][ns] = __builtin_amdgcn_mfma_f32_16x16x32_f16(a1, bf[kk][ns], acc[1][ns], 0, 0, 0);
    }
  }
}

template <int SS, int SW, int KSTEPS>
__device__ __forceinline__ void mlp_compute(const f16* hsrc,
                                            const f16* __restrict__ wt,
                                            const float* __restrict__ bias,
                                            f16 (&vals)[2][4][4],
                                            int mg, int ng, int l15, int lk) {
  static_assert(KSTEPS % 2 == 0, "chunked by 2");
  f32x4 acc[2][4] = {};
  const f16* wrow  = wt + (64 * ng + l15) * SW + 8 * lk;
  const f16* arow0 = hsrc + (32 * mg +      l15) * SS + 8 * lk;
  const f16* arow1 = hsrc + (32 * mg + 16 + l15) * SS + 8 * lk;
  #pragma unroll
  for (int c = 0; c < KSTEPS; c += 2)
    mlp_chunk2<SW>(arow0 + c * 32, arow1 + c * 32, wrow + c * 32, acc);
  #pragma unroll
  for (int ms = 0; ms < 2; ++ms)
    #pragma unroll
    for (int ns = 0; ns < 4; ++ns) {
      int col = 64 * ng + 16 * ns + l15;
      float bv = bias[col];
      #pragma unroll
      for (int r = 0; r < 4; ++r)
        vals[ms][ns][r] = (f16)gelu_fast(acc[ms][ns][r] + bv);
    }
}

__device__ __forceinline__ void mlp_store(const f16 (&vals)[2][4][4], f16* hdst, int sD,
                                          int mg, int ng, int l15, int lk) {
  #pragma unroll
  for (int ms = 0; ms < 2; ++ms)
    #pragma unroll
    for (int ns = 0; ns < 4; ++ns) {
      int col = 64 * ng + 16 * ns + l15;
      #pragma unroll
      for (int r = 0; r < 4; ++r) {
        int row = 32 * mg + 16 * ms + 4 * lk + r;     // C/D: col=lane&15, row=4*(lane>>4)+reg
        hdst[row * sD + col] = vals[ms][ns][r];
      }
    }
}

// ---------------- main fused kernel: 68KB LDS overlay, 2 WG/CU (R6/R7 structure) ----------------
__global__ __launch_bounds__(512, 4) void decoder_main(
    const float* __restrict__ fg, const uint32_t* __restrict__ enc2,
    const float4* __restrict__ bilin,
    const f16* __restrict__ w0t, const f16* __restrict__ w1t, const f16* __restrict__ w2t,
    const float* __restrict__ woutt,
    const float* __restrict__ b0, const float* __restrict__ b1, const float* __restrict__ b2,
    const float* __restrict__ bout, float* __restrict__ out) {
  __shared__ __align__(16) unsigned char smem[69632];
  f16* hA = (f16*)smem;                   // h0 (stride S0, 51200B) -> h1 (stride S1) -> h3
  f16* hB = (f16*)(smem + 34816);         // h2 (stride S1)

  const int tid  = threadIdx.x;
  const int lane = tid & 63, wv = tid >> 6;
  const int l15  = lane & 15, lk = lane >> 4;
  const int mg   = wv & 3,    ng = wv >> 2;
  const int bid  = blockIdx.x;
  const int b    = bid >> 9;
  const int n0   = (bid & 511) * TM;

  // ---- phase 0: build h0 = [enc(42) | sampled(128) | zeros(30)] fp16 (R5-verbatim) ----
  for (int i = tid; i < 128 * 21; i += 512) {           // enc cols 0..41 (21 dwords/row)
    int d = i >> 7, r = i & 127;
    ((uint32_t*)((char*)hA + r * 400))[d] = enc2[(size_t)d * NN + n0 + r];
  }
  for (int i = tid; i < 128 * 16; i += 512) {           // zero cols 170..199 (dwords 85..99)
    int d = i & 15, r = i >> 4;
    if (d < 15) ((uint32_t*)((char*)hA + r * 400))[85 + d] = 0u;
  }
  {
    const float* base = fg + (size_t)b * (64 * 64 * 128);
    #pragma unroll 4
    for (int j = 0; j < 16; ++j) {                      // each wave: 16 rows; lanes = 2 channels each
      int r = wv + 8 * j;
      float4 p  = bilin[n0 + r];
      float fy = p.x, fx = p.y;
      int y0 = __float_as_int(p.z), x0 = __float_as_int(p.w);
      int y1 = min(y0 + 1, 63), x1 = min(x0 + 1, 63);
      const float2* v00 = (const float2*)(base + (y0 * 64 + x0) * 128) + lane;
      const float2* v01 = (const float2*)(base + (y0 * 64 + x1) * 128) + lane;
      const float2* v10 = (const float2*)(base + (y1 * 64 + x0) * 128) + lane;
      const float2* v11 = (const float2*)(base + (y1 * 64 + x1) * 128) + lane;
      float w00 = (1.f - fy) * (1.f - fx), w01 = (1.f - fy) * fx;
      float w10 = fy * (1.f - fx),         w11 = fy * fx;
      float2 a = *v00, c = *v01, d2 = *v10, e2 = *v11;
      float s0 = a.x * w00 + c.x * w01 + d2.x * w10 + e2.x * w11;
      float s1 = a.y * w00 + c.y * w01 + d2.y * w10 + e2.y * w11;
      f16 q0 = (f16)s0, q1 = (f16)s1;
      uint32_t u = (uint32_t)__builtin_bit_cast(uint16_t, q0) |
                   ((uint32_t)__builtin_bit_cast(uint16_t, q1) << 16);
      *(uint32_t*)((char*)hA + r * 400 + 84 + 4 * lane) = u;   // cols 42+2*lane
    }
  }
  __syncthreads();

  f16 v[2][4][4];
  // L0: K=192(pad); defer store — h1 overlays h0 after the read barrier
  mlp_compute<S0, S0, 6>(hA, w0t, b0, v, mg, ng, l15, lk);
  __syncthreads();                                   // all h0 reads done
  mlp_store(v, hA, S1, mg, ng, l15, lk);             // h1 -> [0,34816)
  __syncthreads();
  // L1: h1 -> h2 (disjoint regions, direct store)
  mlp_compute<S1, S1, 4>(hA, w1t, b1, v, mg, ng, l15, lk);
  mlp_store(v, hB, S1, mg, ng, l15, lk);             // h2 -> [34816,69632)
  __syncthreads();
  // L2: h2 -> h3 (h1 region is dead, direct store)
  mlp_compute<S1, S1, 4>(hB, w2t, b2, v, mg, ng, l15, lk);
  mlp_store(v, hA, S1, mg, ng, l15, lk);             // h3 -> [0,34816)
  __syncthreads();

  // ---- output layer: 128x3, fp32 vector, coalesced store (R5-verbatim, src=hA) ----
  if (tid < 384) {
    int row = tid / 3, oc = tid - 3 * row;
    const f16*  hr = hA + row * S1;
    const float* wr = woutt + oc * 128;
    float acc = 0.f;
    #pragma unroll
    for (int i = 0; i < 16; ++i) {
      f16x8 hv = *(const f16x8*)(hr + 8 * i);
      float4 wa = *(const float4*)(wr + 8 * i);
      float4 wb = *(const float4*)(wr + 8 * i + 4);
      acc += (float)hv[0] * wa.x + (float)hv[1] * wa.y + (float)hv[2] * wa.z + (float)hv[3] * wa.w
           + (float)hv[4] * wb.x + (float)hv[5] * wb.y + (float)hv[6] * wb.z + (float)hv[7] * wb.w;
    }
    out[((size_t)b * NN + n0 + row) * 3 + oc] = fast_tanh(acc + bout[oc]);
  }
}

extern "C" void kernel_launch(void* const* d_in, const int* in_sizes, int n_in,
                              void* d_out, int out_size, void* d_ws, size_t ws_size,
                              hipStream_t stream) {
  const float* fg     = (const float*)d_in[0];
  const float* coords = (const float*)d_in[1];
  const float* W0 = (const float*)d_in[2]; const float* b0 = (const float*)d_in[3];
  const float* W1 = (const float*)d_in[4]; const float* b1 = (const float*)d_in[5];
  const float* W2 = (const float*)d_in[6]; const float* b2 = (const float*)d_in[7];
  const float* Wo = (const float*)d_in[8]; const float* bo = (const float*)d_in[9];
  char* ws = (char*)d_ws;
  uint32_t* enc2  = (uint32_t*)(ws + WS_ENC);
  float4*   bilin = (float4*)(ws + WS_BILIN);
  f16* w0t = (f16*)(ws + WS_W0T);
  f16* w1t = (f16*)(ws + WS_W1T);
  f16* w2t = (f16*)(ws + WS_W2T);
  float* woutt = (float*)(ws + WS_WOUT);

  prep_misc<<<256, 256, 0, stream>>>(coords, enc2, bilin);
  int prep_items = 128 * S0 + 2 * 128 * S1 + 512;
  prep_w<<<(prep_items + 255) / 256, 256, 0, stream>>>(W0, W1, W2, Wo, w0t, w1t, w2t, woutt);
  decoder_main<<<4096, 512, 0, stream>>>(fg, enc2, bilin, w0t, w1t, w2t, woutt,
      b0, b1, b2, bo, (float*)d_out);
}

// Round 11
// 364.617 us; speedup vs baseline: 1.0599x; 1.0599x over previous
//
#include <hip/hip_runtime.h>
#include <cstdint>
#include <cstddef>

#define NFREQ 10
#define NN    65536
#define ENCD  42       // 2*(1+2*NFREQ)
#define K0    170      // ENCD + 128
#define S0    200      // h0 / W0t stride in fp16 elems (400B rows: 16B-aligned, 2-way banks)
#define S1    136      // hidden-layer stride (272B rows)
#define TM    128      // rows per block

typedef _Float16 f16;
typedef f16  f16x8 __attribute__((ext_vector_type(8)));
typedef float f32x4 __attribute__((ext_vector_type(4)));

// ---- workspace layout (bytes) ----
#define WS_ENC   0u          // uint32 [24][NN] : packed fp16 pairs of enc (cols 2d,2d+1), transposed
#define WS_BILIN 6291456u    // float4 [NN] : {fy, fx, asfloat(y0), asfloat(x0)}
#define WS_W0T   7340032u    // f16 [128][S0]  rows=out, cols=in; in>=170 zeroed
#define WS_W1T   7391232u    // f16 [128][S1]
#define WS_W2T   7426048u    // f16 [128][S1]
#define WS_WOUT  7460864u    // f32 [4][128]   rows=out-col (row 3 zero)

// Epilogue tanh: R1-verbatim (proven numerics; only 384 threads use it).
__device__ __forceinline__ float fast_tanh(float z) {
  z = fminf(fmaxf(z, -10.f), 10.f);           // avoid inf/inf
  float e = __expf(2.f * z);
  return (e - 1.f) * __builtin_amdgcn_rcpf(e + 1.f);
}
// gelu via sigmoid identity (R7-proven): ONE exp2 + ONE rcp, no NaN path.
__device__ __forceinline__ float gelu_fast(float x) {
  float z = 0.7978845608028654f * (x + 0.044715f * x * x * x);
  float e = __builtin_amdgcn_exp2f(-2.8853900817779268f * z);
  return x * __builtin_amdgcn_rcpf(1.f + e);
}

// ---------------- prep: posenc + bilinear params (R1-verbatim) ----------------
__global__ void prep_misc(const float* __restrict__ coords,
                          uint32_t* __restrict__ enc2, float4* __restrict__ bilin) {
  int n = blockIdx.x * blockDim.x + threadIdx.x;
  if (n >= NN) return;
  float cy = coords[2 * n + 0];
  float cx = coords[2 * n + 1];
  float e[48];
  e[0] = cy; e[1] = cx;
  float f = 3.14159265358979323846f;            // freqs[i] = 2^i * pi (exact doubling)
  #pragma unroll
  for (int i = 0; i < NFREQ; ++i) {
    float sy, cyv, sx, cxv;
    sincosf(cy * f, &sy, &cyv);
    sincosf(cx * f, &sx, &cxv);
    e[2 + 4 * i + 0] = sy;  e[2 + 4 * i + 1] = sx;
    e[2 + 4 * i + 2] = cyv; e[2 + 4 * i + 3] = cxv;
    f *= 2.0f;
  }
  #pragma unroll
  for (int k = ENCD; k < 48; ++k) e[k] = 0.f;
  #pragma unroll
  for (int d = 0; d < 24; ++d) {
    f16 lo = (f16)e[2 * d], hi = (f16)e[2 * d + 1];
    uint32_t u = (uint32_t)__builtin_bit_cast(uint16_t, lo) |
                 ((uint32_t)__builtin_bit_cast(uint16_t, hi) << 16);
    enc2[(size_t)d * NN + n] = u;
  }
  float ry = (cy + 1.f) * 0.5f * 63.f;
  float rx = (cx + 1.f) * 0.5f * 63.f;
  ry = fminf(fmaxf(ry, 0.f), 63.f);
  rx = fminf(fmaxf(rx, 0.f), 63.f);
  int y0 = min((int)ry, 62), x0 = min((int)rx, 62);
  bilin[n] = make_float4(ry - (float)y0, rx - (float)x0,
                         __int_as_float(y0), __int_as_float(x0));
}

// ---------------- prep: pack transposed fp16 weights (R1-verbatim) ----------------
__global__ void prep_w(const float* __restrict__ W0, const float* __restrict__ W1,
                       const float* __restrict__ W2, const float* __restrict__ Wo,
                       f16* __restrict__ w0t, f16* __restrict__ w1t,
                       f16* __restrict__ w2t, float* __restrict__ woutt) {
  int i = blockIdx.x * blockDim.x + threadIdx.x;
  const int n0 = 128 * S0, n1 = 128 * S1;
  if (i < n0) {
    int j = i / S0, k = i - j * S0;
    w0t[i] = (k < K0) ? (f16)W0[k * 128 + j] : (f16)0.f;
  } else if (i < n0 + n1) {
    int ii = i - n0; int j = ii / S1, k = ii - j * S1;
    w1t[ii] = (k < 128) ? (f16)W1[k * 128 + j] : (f16)0.f;
  } else if (i < n0 + 2 * n1) {
    int ii = i - n0 - n1; int j = ii / S1, k = ii - j * S1;
    w2t[ii] = (k < 128) ? (f16)W2[k * 128 + j] : (f16)0.f;
  } else if (i < n0 + 2 * n1 + 512) {
    int ii = i - n0 - 2 * n1; int oc = ii >> 7, k = ii & 127;
    woutt[ii] = (oc < 3) ? Wo[k * 3 + oc] : 0.f;
  }
}

// ---------------- fused MLP layer compute (R7-verbatim math) ----------------
template <int SS, int SW, int KSTEPS>
__device__ __forceinline__ void mlp_compute(const f16* hsrc,
                                            const f16* __restrict__ wt,
                                            const float* __restrict__ bias,
                                            f16 (&vals)[2][4][4],
                                            int mg, int ng, int l15, int lk) {
  f32x4 acc[2][4] = {};
  const f16* wrow  = wt + (64 * ng + l15) * SW + 8 * lk;
  const f16* arow0 = hsrc + (32 * mg +      l15) * SS + 8 * lk;
  const f16* arow1 = hsrc + (32 * mg + 16 + l15) * SS + 8 * lk;
  #pragma unroll
  for (int kk = 0; kk < KSTEPS; ++kk) {
    f16x8 a0 = *(const f16x8*)(arow0 + kk * 32);
    f16x8 a1 = *(const f16x8*)(arow1 + kk * 32);
    #pragma unroll
    for (int ns = 0; ns < 4; ++ns) {
      f16x8 bf = *(const f16x8*)(wrow + (16 * ns) * SW + kk * 32);
      acc[0][ns] = __builtin_amdgcn_mfma_f32_16x16x32_f16(a0, bf, acc[0][ns], 0, 0, 0);
      acc[1][ns] = __builtin_amdgcn_mfma_f32_16x16x32_f16(a1, bf, acc[1][ns], 0, 0, 0);
    }
  }
  #pragma unroll
  for (int ms = 0; ms < 2; ++ms)
    #pragma unroll
    for (int ns = 0; ns < 4; ++ns) {
      int col = 64 * ng + 16 * ns + l15;
      float bv = bias[col];
      #pragma unroll
      for (int r = 0; r < 4; ++r)
        vals[ms][ns][r] = (f16)gelu_fast(acc[ms][ns][r] + bv);
    }
}

__device__ __forceinline__ void mlp_store(const f16 (&vals)[2][4][4], f16* hdst, int sD,
                                          int mg, int ng, int l15, int lk) {
  #pragma unroll
  for (int ms = 0; ms < 2; ++ms)
    #pragma unroll
    for (int ns = 0; ns < 4; ++ns) {
      int col = 64 * ng + 16 * ns + l15;
      #pragma unroll
      for (int r = 0; r < 4; ++r) {
        int row = 32 * mg + 16 * ms + 4 * lk + r;     // C/D: col=lane&15, row=4*(lane>>4)+reg
        hdst[row * sD + col] = vals[ms][ns][r];
      }
    }
}

// ---------------- main kernel: FULL defer-store overlay -> 51,200B LDS -> 3 WG/CU ----------------
// Every layer: compute from LDS into regs -> barrier (reads done) -> overwrite the
// SAME buffer -> barrier (writes visible). Peak LDS = h0 = 51,200B; 3 blocks/CU =
// 24 waves (6/SIMD). launch_bounds(512,6) caps VGPR at 85 (current use: 64).
__global__ __launch_bounds__(512, 6) void decoder_main(
    const float* __restrict__ fg, const uint32_t* __restrict__ enc2,
    const float4* __restrict__ bilin,
    const f16* __restrict__ w0t, const f16* __restrict__ w1t, const f16* __restrict__ w2t,
    const float* __restrict__ woutt,
    const float* __restrict__ b0, const float* __restrict__ b1, const float* __restrict__ b2,
    const float* __restrict__ bout, float* __restrict__ out) {
  __shared__ __align__(16) unsigned char smem[51200];
  f16* hA = (f16*)smem;                   // h0 (stride S0) -> h1 -> h2 -> h3 (stride S1)

  const int tid  = threadIdx.x;
  const int lane = tid & 63, wv = tid >> 6;
  const int l15  = lane & 15, lk = lane >> 4;
  const int mg   = wv & 3,    ng = wv >> 2;
  const int bid  = blockIdx.x;
  const int b    = bid >> 9;
  const int n0   = (bid & 511) * TM;

  // ---- phase 0: build h0 = [enc(42) | sampled(128) | zeros(30)] fp16 (R5-verbatim) ----
  for (int i = tid; i < 128 * 21; i += 512) {           // enc cols 0..41 (21 dwords/row)
    int d = i >> 7, r = i & 127;
    ((uint32_t*)((char*)hA + r * 400))[d] = enc2[(size_t)d * NN + n0 + r];
  }
  for (int i = tid; i < 128 * 16; i += 512) {           // zero cols 170..199 (dwords 85..99)
    int d = i & 15, r = i >> 4;
    if (d < 15) ((uint32_t*)((char*)hA + r * 400))[85 + d] = 0u;
  }
  {
    const float* base = fg + (size_t)b * (64 * 64 * 128);
    #pragma unroll 4
    for (int j = 0; j < 16; ++j) {                      // each wave: 16 rows; lanes = 2 channels each
      int r = wv + 8 * j;
      float4 p  = bilin[n0 + r];
      float fy = p.x, fx = p.y;
      int y0 = __float_as_int(p.z), x0 = __float_as_int(p.w);
      int y1 = min(y0 + 1, 63), x1 = min(x0 + 1, 63);
      const float2* v00 = (const float2*)(base + (y0 * 64 + x0) * 128) + lane;
      const float2* v01 = (const float2*)(base + (y0 * 64 + x1) * 128) + lane;
      const float2* v10 = (const float2*)(base + (y1 * 64 + x0) * 128) + lane;
      const float2* v11 = (const float2*)(base + (y1 * 64 + x1) * 128) + lane;
      float w00 = (1.f - fy) * (1.f - fx), w01 = (1.f - fy) * fx;
      float w10 = fy * (1.f - fx),         w11 = fy * fx;
      float2 a = *v00, c = *v01, d2 = *v10, e2 = *v11;
      float s0 = a.x * w00 + c.x * w01 + d2.x * w10 + e2.x * w11;
      float s1 = a.y * w00 + c.y * w01 + d2.y * w10 + e2.y * w11;
      f16 q0 = (f16)s0, q1 = (f16)s1;
      uint32_t u = (uint32_t)__builtin_bit_cast(uint16_t, q0) |
                   ((uint32_t)__builtin_bit_cast(uint16_t, q1) << 16);
      *(uint32_t*)((char*)hA + r * 400 + 84 + 4 * lane) = u;   // cols 42+2*lane
    }
  }
  __syncthreads();

  f16 v[2][4][4];
  // L0: read h0 (K=192 incl. pad) -> regs; overlay h1 onto the same buffer
  mlp_compute<S0, S0, 6>(hA, w0t, b0, v, mg, ng, l15, lk);
  __syncthreads();                                   // all h0 reads done
  mlp_store(v, hA, S1, mg, ng, l15, lk);             // h1
  __syncthreads();                                   // h1 visible
  // L1: read h1 -> regs; overlay h2
  mlp_compute<S1, S1, 4>(hA, w1t, b1, v, mg, ng, l15, lk);
  __syncthreads();                                   // all h1 reads done
  mlp_store(v, hA, S1, mg, ng, l15, lk);             // h2
  __syncthreads();                                   // h2 visible
  // L2: read h2 -> regs; overlay h3
  mlp_compute<S1, S1, 4>(hA, w2t, b2, v, mg, ng, l15, lk);
  __syncthreads();                                   // all h2 reads done
  mlp_store(v, hA, S1, mg, ng, l15, lk);             // h3
  __syncthreads();                                   // h3 visible

  // ---- output layer: 128x3, fp32 vector, coalesced store (R5-verbatim, src=hA) ----
  if (tid < 384) {
    int row = tid / 3, oc = tid - 3 * row;
    const f16*  hr = hA + row * S1;
    const float* wr = woutt + oc * 128;
    float acc = 0.f;
    #pragma unroll
    for (int i = 0; i < 16; ++i) {
      f16x8 hv = *(const f16x8*)(hr + 8 * i);
      float4 wa = *(const float4*)(wr + 8 * i);
      float4 wb = *(const float4*)(wr + 8 * i + 4);
      acc += (float)hv[0] * wa.x + (float)hv[1] * wa.y + (float)hv[2] * wa.z + (float)hv[3] * wa.w
           + (float)hv[4] * wb.x + (float)hv[5] * wb.y + (float)hv[6] * wb.z + (float)hv[7] * wb.w;
    }
    out[((size_t)b * NN + n0 + row) * 3 + oc] = fast_tanh(acc + bout[oc]);
  }
}

extern "C" void kernel_launch(void* const* d_in, const int* in_sizes, int n_in,
                              void* d_out, int out_size, void* d_ws, size_t ws_size,
                              hipStream_t stream) {
  const float* fg     = (const float*)d_in[0];
  const float* coords = (const float*)d_in[1];
  const float* W0 = (const float*)d_in[2]; const float* b0 = (const float*)d_in[3];
  const float* W1 = (const float*)d_in[4]; const float* b1 = (const float*)d_in[5];
  const float* W2 = (const float*)d_in[6]; const float* b2 = (const float*)d_in[7];
  const float* Wo = (const float*)d_in[8]; const float* bo = (const float*)d_in[9];
  char* ws = (char*)d_ws;
  uint32_t* enc2  = (uint32_t*)(ws + WS_ENC);
  float4*   bilin = (float4*)(ws + WS_BILIN);
  f16* w0t = (f16*)(ws + WS_W0T);
  f16* w1t = (f16*)(ws + WS_W1T);
  f16* w2t = (f16*)(ws + WS_W2T);
  float* woutt = (float*)(ws + WS_WOUT);

  prep_misc<<<256, 256, 0, stream>>>(coords, enc2, bilin);
  int prep_items = 128 * S0 + 2 * 128 * S1 + 512;
  prep_w<<<(prep_items + 255) / 256, 256, 0, stream>>>(W0, W1, W2, Wo, w0t, w1t, w2t, woutt);
  decoder_main<<<4096, 512, 0, stream>>>(fg, enc2, bilin, w0t, w1t, w2t, woutt,
      b0, b1, b2, bo, (float*)d_out);
}